// Round 15
// baseline (311.945 us; speedup 1.0000x reference)
//
#include <hip/hip_runtime.h>
#include <math.h>

#define B_ 256
#define L_ 256
#define V_ 2048
#define DIN_ 128
#define H_ 256
#define NODES_ 511

typedef _Float16 half8 __attribute__((ext_vector_type(8)));
typedef float f32x4 __attribute__((ext_vector_type(4)));

__device__ __forceinline__ float sigm(float x) { return 1.f / (1.f + __expf(-x)); }
__device__ __forceinline__ float tanh_f(float x) {
    float xc = fminf(fmaxf(x, -15.f), 15.f);
    float e = __expf(2.f * xc);
    return (e - 1.f) / (e + 1.f);
}
__device__ __forceinline__ void gload16(const void* g, void* l) {
    __builtin_amdgcn_global_load_lds((const __attribute__((address_space(1))) unsigned int*)g,
                                     (__attribute__((address_space(3))) unsigned int*)l, 16, 0, 0);
}
template<int N> __device__ __forceinline__ void vwaitN() {
    asm volatile("s_waitcnt vmcnt(%0)" :: "i"(N) : "memory");
}

// WT[nn][k] fp16: FULL fused weights. nn = g*256+t (g:0=i,1=o,2=u,3=f0,4=f1),
// k: [0,128)=x, [128,384)=h1, [384,640)=h2
__global__ void build_WT(_Float16* __restrict__ WT,
    const float* __restrict__ Wioux, const float* __restrict__ Wfx,
    const float* __restrict__ Wiouh1, const float* __restrict__ Wfh11, const float* __restrict__ Wfh21,
    const float* __restrict__ Wiouh2, const float* __restrict__ Wfh12, const float* __restrict__ Wfh22)
{
    int e = blockIdx.x * 256 + threadIdx.x;   // < 1280*640
    int nn = e / 640, k = e - nn * 640;
    int g = nn >> 8, t = nn & 255;
    float v;
    if (k < 128) {
        v = (g < 3) ? Wioux[k * 768 + nn] : Wfx[k * 256 + t];
    } else if (k < 384) {
        int kp = k - 128;
        v = (g < 3) ? Wiouh1[kp * 768 + nn] : ((g == 3) ? Wfh11[kp * 256 + t] : Wfh21[kp * 256 + t]);
    } else {
        int kp = k - 384;
        v = (g < 3) ? Wiouh2[kp * 768 + nn] : ((g == 3) ? Wfh12[kp * 256 + t] : Wfh22[kp * 256 + t]);
    }
    WT[e] = (_Float16)v;
}

__global__ void build_bias(float* __restrict__ bias,
    const float* __restrict__ bioux, const float* __restrict__ biouh1, const float* __restrict__ biouh2,
    const float* __restrict__ bfx, const float* __restrict__ bfh11, const float* __restrict__ bfh12,
    const float* __restrict__ bfh21, const float* __restrict__ bfh22)
{
    int e = blockIdx.x * 256 + threadIdx.x;
    if (e >= 1280) return;
    int g = e >> 8, t = e & 255;
    float v;
    if (g < 3)       v = bioux[e] + biouh1[e] + biouh2[e];
    else if (g == 3) v = bfx[t] + bfh11[t] + bfh12[t];
    else             v = bfx[t] + bfh21[t] + bfh22[t];
    bias[e] = v;
}

// emb -> fp16, row 0 zeroed
__global__ void build_embh(_Float16* __restrict__ EH, const float* __restrict__ emb) {
    int e = blockIdx.x * 256 + threadIdx.x;   // < 2048*128
    EH[e] = (e < DIN_) ? (_Float16)0.f : (_Float16)emb[e];
}

// tab[id][col] f32 = emb(id,:) @ Wx_fused(:,col) + bias_total(col)
__global__ __launch_bounds__(256) void build_table(float* __restrict__ tab, const float* __restrict__ emb,
    const float* __restrict__ Wioux, const float* __restrict__ Wfx,
    const float* __restrict__ bioux, const float* __restrict__ biouh1, const float* __restrict__ biouh2,
    const float* __restrict__ bfx, const float* __restrict__ bfh11, const float* __restrict__ bfh12,
    const float* __restrict__ bfh21, const float* __restrict__ bfh22)
{
    __shared__ float As[64][33];
    __shared__ float Ws[32][65];
    const int tid = threadIdx.x, tx = tid & 15, ty = tid >> 4;
    const int i0 = blockIdx.x * 64, c0 = blockIdx.y * 64;
    const int g = c0 >> 8;
    float acc[4][4];
    #pragma unroll
    for (int i = 0; i < 4; ++i)
        #pragma unroll
        for (int j = 0; j < 4; ++j) acc[i][j] = 0.f;

    for (int k0 = 0; k0 < 128; k0 += 32) {
        #pragma unroll
        for (int it = 0; it < 2; ++it) {
            int f = tid + it * 256;
            int row = f >> 3, kk = (f & 7) * 4;
            int gr = i0 + row;
            float4 av = (gr == 0) ? make_float4(0.f, 0.f, 0.f, 0.f)
                                  : *(const float4*)(emb + (size_t)gr * 128 + k0 + kk);
            As[row][kk] = av.x; As[row][kk + 1] = av.y; As[row][kk + 2] = av.z; As[row][kk + 3] = av.w;
            int k = f >> 4, cc = (f & 15) * 4;
            int col = c0 + cc;
            float4 wv = (g < 3) ? *(const float4*)(Wioux + (size_t)(k0 + k) * 768 + col)
                                : *(const float4*)(Wfx + (size_t)(k0 + k) * 256 + (col & 255));
            Ws[k][cc] = wv.x; Ws[k][cc + 1] = wv.y; Ws[k][cc + 2] = wv.z; Ws[k][cc + 3] = wv.w;
        }
        __syncthreads();
        #pragma unroll 8
        for (int k = 0; k < 32; ++k) {
            float a[4], w[4];
            #pragma unroll
            for (int i = 0; i < 4; ++i) a[i] = As[ty * 4 + i][k];
            #pragma unroll
            for (int j = 0; j < 4; ++j) w[j] = Ws[k][tx * 4 + j];
            #pragma unroll
            for (int i = 0; i < 4; ++i)
                #pragma unroll
                for (int j = 0; j < 4; ++j) acc[i][j] = fmaf(a[i], w[j], acc[i][j]);
        }
        __syncthreads();
    }
    #pragma unroll
    for (int j = 0; j < 4; ++j) {
        int col = c0 + tx * 4 + j; int t = col & 255;
        float bs = (g < 3) ? (bioux[col] + biouh1[col] + biouh2[col])
                 : (g == 3) ? (bfx[t] + bfh11[t] + bfh12[t])
                            : (bfx[t] + bfh21[t] + bfh22[t]);
        #pragma unroll
        for (int i = 0; i < 4; ++i)
            tab[(size_t)(i0 + ty * 4 + i) * 1280 + col] = acc[i][j] + bs;
    }
}

// Level-0 result depends only on token id: H0h/H0c[id][t]
__global__ void build_h0c0(const float* __restrict__ tab, _Float16* __restrict__ H0h, float* __restrict__ H0c) {
    int id = blockIdx.x, t = threadIdx.x;
    const float* tp = tab + (size_t)id * 1280 + t;
    float vi = sigm(tp[0]), vo = sigm(tp[256]), vu = tanh_f(tp[512]);
    float c = vi * vu;
    H0h[id * 256 + t] = (_Float16)(vo * tanh_f(c));
    H0c[id * 256 + t] = c;
}

// G[id][np] f32 = H0h(id,:) @ [Wh1 | Wh2](:,np). M=2048, K=256, N=2560.
// np in [0,1280): Wh1 (k-off 128); np in [1280,2560): Wh2 (k-off 384).
// Block: 4 waves x 64 rows (RT=4) x 64 cols (CT=4). BK=32, 8 steps, 3-buf counted pipeline.
__global__ __launch_bounds__(256, 2) void build_G(
    const _Float16* __restrict__ WT, const _Float16* __restrict__ H0h, float* __restrict__ G)
{
    __shared__ __align__(16) char Asm[3][256 * 64];
    __shared__ __align__(16) char Bsm[3][4096];
    const int tid = threadIdx.x, lane = tid & 63, wid = tid >> 6;
    const int l15 = lane & 15, lg = lane >> 4;
    const int rowB = blockIdx.x * 256;
    const int C0 = blockIdx.y * 64;

    const unsigned segOff = (unsigned)((((lane & 3) ^ ((lane >> 3) & 3))) * 16);
    unsigned srcA[4];
    #pragma unroll
    for (int i = 0; i < 4; ++i) {
        int rl = (wid * 4 + i) * 16 + (lane >> 2);
        srcA[i] = (unsigned)(rowB + rl) * 512u + segOff;
    }
    unsigned bsrc;
    {
        int cc = tid >> 2, j = tid & 3;
        int np = C0 + cc;
        int part = (np >= 1280) ? 1 : 0;
        int nn = np - part * 1280;
        bsrc = (unsigned)((nn * 640 + 128 + part * 256 + ((j ^ ((cc >> 1) & 3)) * 8)) * 2);
    }
    const char* hPB = (const char*)H0h;
    const char* wPB = (const char*)WT;

    f32x4 acc[4][4];
    #pragma unroll
    for (int rt = 0; rt < 4; ++rt)
        #pragma unroll
        for (int ct = 0; ct < 4; ++ct) acc[rt][ct] = (f32x4)0.f;

    const int xw = (l15 >> 1) & 3;

    auto STAGE = [&](int st, int buf) {
        #pragma unroll
        for (int i = 0; i < 4; ++i)
            gload16(hPB + srcA[i] + (unsigned)st * 64u, &Asm[buf][(wid * 4 + i) * 1024 + lane * 16]);
        gload16(wPB + bsrc + (unsigned)st * 64u, &Bsm[buf][tid * 16]);
    };
    auto COMPUTE = [&](int buf) {
        half8 aF[4];
        #pragma unroll
        for (int rt = 0; rt < 4; ++rt)
            aF[rt] = *(const half8*)&Asm[buf][(wid * 64 + rt * 16 + l15) * 64 + ((lg ^ xw) * 16)];
        #pragma unroll
        for (int ct = 0; ct < 4; ++ct) {
            int cc = ct * 16 + l15;
            half8 bF = *(const half8*)&Bsm[buf][cc * 64 + ((lg ^ ((cc >> 1) & 3)) * 16)];
            #pragma unroll
            for (int rt = 0; rt < 4; ++rt)
                acc[rt][ct] = __builtin_amdgcn_mfma_f32_16x16x32_f16(aF[rt], bF, acc[rt][ct], 0, 0, 0);
        }
    };
    auto WAITB = [&](bool counted) {
        if (counted) vwaitN<5>(); else vwaitN<0>();
        __builtin_amdgcn_s_barrier();
        __builtin_amdgcn_sched_barrier(0);
    };

    STAGE(0, 0); STAGE(1, 1); WAITB(true);
    #pragma unroll
    for (int S = 0; S < 8; ++S) {
        if (S + 2 < 8) STAGE(S + 2, (S + 2) % 3);
        COMPUTE(S % 3);
        if (S < 7) WAITB(S + 2 < 8);
    }

    #pragma unroll
    for (int rt = 0; rt < 4; ++rt)
        #pragma unroll
        for (int ct = 0; ct < 4; ++ct)
            #pragma unroll
            for (int q = 0; q < 4; ++q)
                G[(size_t)(rowB + wid * 64 + rt * 16 + lg * 4 + q) * 2560 + C0 + ct * 16 + l15] = acc[rt][ct][q];
}

// Level-1 as pure gather-add-gate: pre[g] = tab[idp] + G[idA][g*256+c] + G[idB][1280+g*256+c].
// Grid = rowblocks(128) x panels(16), bid = rb*16+p -> panel p on XCD p%8 (L2-local slices).
__global__ __launch_bounds__(256) void lvl1_combine(
    const float* __restrict__ tab, const float* __restrict__ G,
    const float* __restrict__ H0c, const int* __restrict__ ids,
    _Float16* __restrict__ h_out, float* __restrict__ c_out)
{
    const int tid = threadIdx.x;
    const int l15 = tid & 15, rq = tid >> 4;
    const int bid = blockIdx.x;
    const int p = bid & 15, rb = bid >> 4;
    const int col = p * 16 + l15;
    #pragma unroll 4
    for (int it = 0; it < 16; ++it) {
        int row = rb * 256 + it * 16 + rq;
        int b = row >> 7, j = row & 127;
        const int* idr = ids + b * NODES_;
        int idp = idr[256 + j];
        int idA = idr[2 * j];
        int idB = idr[2 * j + 1];
        const float* tp = tab + (size_t)idp * 1280 + col;
        const float* g1 = G + (size_t)idA * 2560 + col;
        const float* g2 = G + (size_t)idB * 2560 + 1280 + col;
        float pre0 = tp[0]    + g1[0]    + g2[0];
        float pre1 = tp[256]  + g1[256]  + g2[256];
        float pre2 = tp[512]  + g1[512]  + g2[512];
        float pre3 = tp[768]  + g1[768]  + g2[768];
        float pre4 = tp[1024] + g1[1024] + g2[1024];
        float c1 = H0c[idA * 256 + col], c2 = H0c[idB * 256 + col];
        float vi = sigm(pre0), vo = sigm(pre1), vu = tanh_f(pre2);
        float vf0 = sigm(pre3), vf1 = sigm(pre4);
        float c = vi * vu + vf0 * c1 + vf1 * c2;
        h_out[(size_t)row * 256 + col] = (_Float16)(vo * tanh_f(c));
        c_out[(size_t)row * 256 + col] = c;
    }
}

// Tree-level cell vJ (R13): K=640, m97-structure + counted-vmcnt 3-buffer pipeline.
// Used for levels 2-8 only (LVL1 path retired).
template<bool LVL1, int RT>
__global__ __launch_bounds__(256, (RT >= 4 ? 2 : 4)) void cellJ(
    const _Float16* __restrict__ WT, const float* __restrict__ bias,
    const _Float16* __restrict__ embh, const int* __restrict__ ids,
    const _Float16* __restrict__ h_prev, const float* __restrict__ c_prev,
    _Float16* __restrict__ h_out, float* __restrict__ c_out,
    int n, int ln, int off, int nx)
{
    constexpr int BM = RT * 64;
    __shared__ __align__(16) char Asm[3][BM * 64];
    __shared__ __align__(16) char Bsm[3][5120];
    const int tid = threadIdx.x, lane = tid & 63, wid = tid >> 6;
    const int l15 = lane & 15, lg = lane >> 4;

    int bid = blockIdx.x, x, y;
    if ((nx & 7) == 0) { int xcd = bid & 7, rank = bid >> 3; x = xcd * (nx >> 3) + (rank >> 4); y = rank & 15; }
    else { x = bid >> 4; y = bid & 15; }
    const int rowB = x * BM;
    const int t0 = y * 16;

    const unsigned segOff = (unsigned)((((lane & 3) ^ ((lane >> 3) & 3))) * 16);
    unsigned srcX[RT], srcA[RT];
    #pragma unroll
    for (int i = 0; i < RT; ++i) {
        int rl = (wid * RT + i) * 16 + (lane >> 2);
        int r = rowB + rl;
        int b = r >> ln, j = r & (n - 1);
        srcX[i] = (unsigned)ids[b * NODES_ + off + j] * 256u + segOff;
        srcA[i] = (unsigned)r * 1024u + segOff;
    }
    unsigned bsrc0, bsrc1 = 0;
    {
        int nr = tid >> 2, j = tid & 3;
        int ng = (nr >> 4) * 256 + t0 + (nr & 15);
        bsrc0 = (unsigned)((ng * 640 + ((j ^ ((nr >> 1) & 3)) * 8)) * 2);
        if (wid == 0) {
            int ng2 = 1024 + t0 + (tid >> 2);
            int seg2 = (tid & 3) ^ ((tid >> 3) & 3);
            bsrc1 = (unsigned)((ng2 * 640 + seg2 * 8) * 2);
        }
    }
    const char* hPB = (const char*)h_prev;
    const char* xPB = (const char*)embh;
    const char* wPB = (const char*)WT;

    f32x4 acc[RT][5];
    #pragma unroll
    for (int rt = 0; rt < RT; ++rt)
        #pragma unroll
        for (int g = 0; g < 5; ++g) acc[rt][g] = (f32x4)0.f;

    const int xw = (l15 >> 1) & 3;

    auto STAGE = [&](int st, int buf) {
        #pragma unroll
        for (int i = 0; i < RT; ++i) {
            const char* bp; unsigned sa;
            if (st < 4) { bp = xPB; sa = srcX[i] + (unsigned)st * 64u; }
            else { bp = hPB; sa = srcA[i] + (unsigned)(st - 4) * 64u; }
            gload16(bp + sa, &Asm[buf][(wid * RT + i) * 1024 + lane * 16]);
        }
        gload16(wPB + bsrc0 + (unsigned)st * 64u, &Bsm[buf][tid * 16]);
        if (wid == 0) gload16(wPB + bsrc1 + (unsigned)st * 64u, &Bsm[buf][4096 + tid * 16]);
    };
    auto COMPUTE = [&](int buf) {
        half8 aF[RT];
        #pragma unroll
        for (int rt = 0; rt < RT; ++rt)
            aF[rt] = *(const half8*)&Asm[buf][(wid * RT * 16 + rt * 16 + l15) * 64 + ((lg ^ xw) * 16)];
        #pragma unroll
        for (int g = 0; g < 5; ++g) {
            half8 bF = *(const half8*)&Bsm[buf][(g * 16 + l15) * 64 + ((lg ^ xw) * 16)];
            #pragma unroll
            for (int rt = 0; rt < RT; ++rt)
                acc[rt][g] = __builtin_amdgcn_mfma_f32_16x16x32_f16(aF[rt], bF, acc[rt][g], 0, 0, 0);
        }
    };
    auto WAITB = [&](bool counted) {
        if (counted) { if (wid == 0) vwaitN<RT + 2>(); else vwaitN<RT + 1>(); }
        else vwaitN<0>();
        __builtin_amdgcn_s_barrier();
        __builtin_amdgcn_sched_barrier(0);
    };

    STAGE(0, 0);
    STAGE(1, 1);
    WAITB(true);

    #pragma unroll
    for (int S = 0; S < 20; ++S) {
        if (S + 2 < 20) STAGE(S + 2, (S + 2) % 3);
        COMPUTE(S % 3);
        if (S < 19) WAITB(S + 2 < 20);
    }

    const int tcol = t0 + l15;
    const float b0 = bias[tcol], b1 = bias[256 + tcol], b2 = bias[512 + tcol];
    const float b3 = bias[768 + tcol], b4 = bias[1024 + tcol];
    #pragma unroll
    for (int rt = 0; rt < RT; ++rt) {
        #pragma unroll
        for (int q = 0; q < 4; ++q) {
            int row = rowB + wid * (RT * 16) + rt * 16 + lg * 4 + q;
            const float* cpp = c_prev + (size_t)row * 512 + tcol;
            float c1 = cpp[0], c2 = cpp[256];
            float vi  = sigm(acc[rt][0][q] + b0);
            float vo  = sigm(acc[rt][1][q] + b1);
            float vu  = tanh_f(acc[rt][2][q] + b2);
            float vf0 = sigm(acc[rt][3][q] + b3);
            float vf1 = sigm(acc[rt][4][q] + b4);
            float c = vi * vu + vf0 * c1 + vf1 * c2;
            size_t ob = (size_t)row * 256 + tcol;
            h_out[ob] = (_Float16)(vo * tanh_f(c));
            c_out[ob] = c;
        }
    }
}

// pred[b] = relu(h_root[b] @ Wl1 + bl1) @ Wl2 + bl2
__global__ void head_kernel(const _Float16* __restrict__ hroot,
    const float* __restrict__ Wl1, const float* __restrict__ bl1,
    const float* __restrict__ Wl2, const float* __restrict__ bl2,
    float* __restrict__ out)
{
    __shared__ float hrow[H_];
    __shared__ float red[256];
    int b = blockIdx.x; int tid = threadIdx.x;
    hrow[tid] = (float)hroot[(size_t)b * H_ + tid];
    __syncthreads();
    float v = 0.f;
    if (tid < 100) {
        float s = bl1[tid];
        for (int k = 0; k < H_; ++k) s = fmaf(hrow[k], Wl1[k * 100 + tid], s);
        v = fmaxf(s, 0.f) * Wl2[tid];
    }
    red[tid] = v;
    __syncthreads();
    for (int s = 128; s > 0; s >>= 1) { if (tid < s) red[tid] += red[tid + s]; __syncthreads(); }
    if (tid == 0) out[b] = red[0] + bl2[0];
}

extern "C" void kernel_launch(void* const* d_in, const int* in_sizes, int n_in,
                              void* d_out, int out_size, void* d_ws, size_t ws_size,
                              hipStream_t stream) {
    const int*   ids    = (const int*)d_in[0];
    const float* emb    = (const float*)d_in[1];
    const float* Wioux  = (const float*)d_in[2];
    const float* bioux  = (const float*)d_in[3];
    const float* Wiouh1 = (const float*)d_in[4];
    const float* biouh1 = (const float*)d_in[5];
    const float* Wiouh2 = (const float*)d_in[6];
    const float* biouh2 = (const float*)d_in[7];
    const float* Wfx    = (const float*)d_in[8];
    const float* bfx    = (const float*)d_in[9];
    const float* Wfh11  = (const float*)d_in[10];
    const float* bfh11  = (const float*)d_in[11];
    const float* Wfh12  = (const float*)d_in[12];
    const float* bfh12  = (const float*)d_in[13];
    const float* Wfh21  = (const float*)d_in[14];
    const float* bfh21  = (const float*)d_in[15];
    const float* Wfh22  = (const float*)d_in[16];
    const float* bfh22  = (const float*)d_in[17];
    const float* Wl1    = (const float*)d_in[18];
    const float* bl1    = (const float*)d_in[19];
    const float* Wl2    = (const float*)d_in[20];
    const float* bl2    = (const float*)d_in[21];
    float* out = (float*)d_out;

    // ws layout (bytes)
    char* wsb = (char*)d_ws;
    _Float16* WT   = (_Float16*)(wsb);                   //  1,638,400
    _Float16* embh = (_Float16*)(wsb + 1638400);         //    524,288
    float*    bias = (float*)(wsb + 2162688);            //      5,120
    float*    tab  = (float*)(wsb + 2167808);            // 10,485,760
    _Float16* H0h  = (_Float16*)(wsb + 12653568);        //  1,048,576
    float*    H0c  = (float*)(wsb + 13702144);           //  2,097,152
    _Float16* hA   = (_Float16*)(wsb + 15799296);        //  8,388,608
    _Float16* hB   = (_Float16*)(wsb + 24187904);        // 16,777,216
    float*    cA   = (float*)(wsb + 40965120);           // 16,777,216
    float*    cB   = (float*)(wsb + 57742336);           // 33,554,432
    float*    G    = (float*)(wsb + 91296768);           // 20,971,520 -> ends 112,268,288

    build_WT<<<dim3(3200), 256, 0, stream>>>(WT, Wioux, Wfx, Wiouh1, Wfh11, Wfh21, Wiouh2, Wfh12, Wfh22);
    build_bias<<<dim3(5), 256, 0, stream>>>(bias, bioux, biouh1, biouh2, bfx, bfh11, bfh12, bfh21, bfh22);
    build_embh<<<dim3(1024), 256, 0, stream>>>(embh, emb);
    build_table<<<dim3(32, 20), 256, 0, stream>>>(tab, emb, Wioux, Wfx,
        bioux, biouh1, biouh2, bfx, bfh11, bfh12, bfh21, bfh22);
    build_h0c0<<<dim3(2048), 256, 0, stream>>>(tab, H0h, H0c);
    build_G<<<dim3(8, 40), 256, 0, stream>>>(WT, H0h, G);

    // level 1 via gather-add-gate
    lvl1_combine<<<dim3(2048), 256, 0, stream>>>(tab, G, H0c, ids, hB, cB);

    _Float16 *hp = hB, *hn = hA;
    float    *cp = cB, *cn = cA;
    int off = 384, n = 64, ln = 6;
    for (int lvl = 2; lvl <= 8; ++lvl) {
        int M = B_ * n;
        if (M >= 2048) {                 // lvl 2-5: RT=4, BM=256
            int nx = M / 256;
            cellJ<false, 4><<<dim3(nx * 16), 256, 0, stream>>>(WT, bias, embh, ids, hp, cp, hn, cn, n, ln, off, nx);
        } else if (M >= 1024) {          // lvl 6: RT=2, BM=128
            int nx = M / 128;
            cellJ<false, 2><<<dim3(nx * 16), 256, 0, stream>>>(WT, bias, embh, ids, hp, cp, hn, cn, n, ln, off, nx);
        } else {                         // lvl 7-8: RT=1, BM=64
            int nx = M / 64;
            cellJ<false, 1><<<dim3(nx * 16), 256, 0, stream>>>(WT, bias, embh, ids, hp, cp, hn, cn, n, ln, off, nx);
        }
        off += n; n >>= 1; --ln;
        _Float16* t1 = hp; hp = hn; hn = t1;
        float*    t2 = cp; cp = cn; cn = t2;
    }

    head_kernel<<<dim3(256), 256, 0, stream>>>(hp, Wl1, bl1, Wl2, bl2, out);
}

// Round 16
// 243.270 us; speedup vs baseline: 1.2823x; 1.2823x over previous
//
#include <hip/hip_runtime.h>
#include <math.h>

#define B_ 256
#define L_ 256
#define V_ 2048
#define DIN_ 128
#define H_ 256
#define NODES_ 511

typedef _Float16 half8 __attribute__((ext_vector_type(8)));
typedef float f32x4 __attribute__((ext_vector_type(4)));

__device__ __forceinline__ float sigm(float x) { return 1.f / (1.f + __expf(-x)); }
__device__ __forceinline__ float tanh_f(float x) {
    float xc = fminf(fmaxf(x, -15.f), 15.f);
    float e = __expf(2.f * xc);
    return (e - 1.f) / (e + 1.f);
}
__device__ __forceinline__ void gload16(const void* g, void* l) {
    __builtin_amdgcn_global_load_lds((const __attribute__((address_space(1))) unsigned int*)g,
                                     (__attribute__((address_space(3))) unsigned int*)l, 16, 0, 0);
}
template<int N> __device__ __forceinline__ void vwaitN() {
    asm volatile("s_waitcnt vmcnt(%0)" :: "i"(N) : "memory");
}

// WT[nn][k] fp16: FULL fused weights. nn = g*256+t (g:0=i,1=o,2=u,3=f0,4=f1),
// k: [0,128)=x, [128,384)=h1, [384,640)=h2
__global__ void build_WT(_Float16* __restrict__ WT,
    const float* __restrict__ Wioux, const float* __restrict__ Wfx,
    const float* __restrict__ Wiouh1, const float* __restrict__ Wfh11, const float* __restrict__ Wfh21,
    const float* __restrict__ Wiouh2, const float* __restrict__ Wfh12, const float* __restrict__ Wfh22)
{
    int e = blockIdx.x * 256 + threadIdx.x;   // < 1280*640
    int nn = e / 640, k = e - nn * 640;
    int g = nn >> 8, t = nn & 255;
    float v;
    if (k < 128) {
        v = (g < 3) ? Wioux[k * 768 + nn] : Wfx[k * 256 + t];
    } else if (k < 384) {
        int kp = k - 128;
        v = (g < 3) ? Wiouh1[kp * 768 + nn] : ((g == 3) ? Wfh11[kp * 256 + t] : Wfh21[kp * 256 + t]);
    } else {
        int kp = k - 384;
        v = (g < 3) ? Wiouh2[kp * 768 + nn] : ((g == 3) ? Wfh12[kp * 256 + t] : Wfh22[kp * 256 + t]);
    }
    WT[e] = (_Float16)v;
}

__global__ void build_bias(float* __restrict__ bias,
    const float* __restrict__ bioux, const float* __restrict__ biouh1, const float* __restrict__ biouh2,
    const float* __restrict__ bfx, const float* __restrict__ bfh11, const float* __restrict__ bfh12,
    const float* __restrict__ bfh21, const float* __restrict__ bfh22)
{
    int e = blockIdx.x * 256 + threadIdx.x;
    if (e >= 1280) return;
    int g = e >> 8, t = e & 255;
    float v;
    if (g < 3)       v = bioux[e] + biouh1[e] + biouh2[e];
    else if (g == 3) v = bfx[t] + bfh11[t] + bfh12[t];
    else             v = bfx[t] + bfh21[t] + bfh22[t];
    bias[e] = v;
}

// emb -> fp16, row 0 zeroed
__global__ void build_embh(_Float16* __restrict__ EH, const float* __restrict__ emb) {
    int e = blockIdx.x * 256 + threadIdx.x;   // < 2048*128
    EH[e] = (e < DIN_) ? (_Float16)0.f : (_Float16)emb[e];
}

// tabP[id][panel][gate][16] f32 = emb(id,:) @ Wx_fused + bias_total, panel-contiguous.
__global__ __launch_bounds__(256) void build_table(float* __restrict__ tabP, const float* __restrict__ emb,
    const float* __restrict__ Wioux, const float* __restrict__ Wfx,
    const float* __restrict__ bioux, const float* __restrict__ biouh1, const float* __restrict__ biouh2,
    const float* __restrict__ bfx, const float* __restrict__ bfh11, const float* __restrict__ bfh12,
    const float* __restrict__ bfh21, const float* __restrict__ bfh22)
{
    __shared__ float As[64][33];
    __shared__ float Ws[32][65];
    const int tid = threadIdx.x, tx = tid & 15, ty = tid >> 4;
    const int i0 = blockIdx.x * 64, c0 = blockIdx.y * 64;
    const int g = c0 >> 8;
    float acc[4][4];
    #pragma unroll
    for (int i = 0; i < 4; ++i)
        #pragma unroll
        for (int j = 0; j < 4; ++j) acc[i][j] = 0.f;

    for (int k0 = 0; k0 < 128; k0 += 32) {
        #pragma unroll
        for (int it = 0; it < 2; ++it) {
            int f = tid + it * 256;
            int row = f >> 3, kk = (f & 7) * 4;
            int gr = i0 + row;
            float4 av = (gr == 0) ? make_float4(0.f, 0.f, 0.f, 0.f)
                                  : *(const float4*)(emb + (size_t)gr * 128 + k0 + kk);
            As[row][kk] = av.x; As[row][kk + 1] = av.y; As[row][kk + 2] = av.z; As[row][kk + 3] = av.w;
            int k = f >> 4, cc = (f & 15) * 4;
            int col = c0 + cc;
            float4 wv = (g < 3) ? *(const float4*)(Wioux + (size_t)(k0 + k) * 768 + col)
                                : *(const float4*)(Wfx + (size_t)(k0 + k) * 256 + (col & 255));
            Ws[k][cc] = wv.x; Ws[k][cc + 1] = wv.y; Ws[k][cc + 2] = wv.z; Ws[k][cc + 3] = wv.w;
        }
        __syncthreads();
        #pragma unroll 8
        for (int k = 0; k < 32; ++k) {
            float a[4], w[4];
            #pragma unroll
            for (int i = 0; i < 4; ++i) a[i] = As[ty * 4 + i][k];
            #pragma unroll
            for (int j = 0; j < 4; ++j) w[j] = Ws[k][tx * 4 + j];
            #pragma unroll
            for (int i = 0; i < 4; ++i)
                #pragma unroll
                for (int j = 0; j < 4; ++j) acc[i][j] = fmaf(a[i], w[j], acc[i][j]);
        }
        __syncthreads();
    }
    #pragma unroll
    for (int j = 0; j < 4; ++j) {
        int col = c0 + tx * 4 + j; int t = col & 255;
        int p = t >> 4, q = t & 15;
        float bs = (g < 3) ? (bioux[col] + biouh1[col] + biouh2[col])
                 : (g == 3) ? (bfx[t] + bfh11[t] + bfh12[t])
                            : (bfx[t] + bfh21[t] + bfh22[t]);
        #pragma unroll
        for (int i = 0; i < 4; ++i) {
            int id = i0 + ty * 4 + i;
            tabP[((size_t)(id * 16 + p) * 5 + g) * 16 + q] = acc[i][j] + bs;
        }
    }
}

// Level-0 result depends only on token id: H0h/H0c[id][t] (reads panel-contiguous tabP)
__global__ void build_h0c0(const float* __restrict__ tabP, _Float16* __restrict__ H0h, float* __restrict__ H0c) {
    int id = blockIdx.x, t = threadIdx.x;
    int p = t >> 4, q = t & 15;
    const float* tp = tabP + ((size_t)(id * 16 + p) * 5) * 16 + q;
    float vi = sigm(tp[0]), vo = sigm(tp[16]), vu = tanh_f(tp[32]);
    float c = vi * vu;
    H0h[id * 256 + t] = (_Float16)(vo * tanh_f(c));
    H0c[id * 256 + t] = c;
}

// Gp[id][part][panel][gate][16] f32 = H0h(id,:) @ [Wh1 | Wh2]. M=2048, K=256, N=2560.
// part 0 = h1 (k-off 128), part 1 = h2 (k-off 384). Panel-contiguous output.
__global__ __launch_bounds__(256, 2) void build_G(
    const _Float16* __restrict__ WT, const _Float16* __restrict__ H0h, float* __restrict__ Gp)
{
    __shared__ __align__(16) char Asm[3][256 * 64];
    __shared__ __align__(16) char Bsm[3][4096];
    const int tid = threadIdx.x, lane = tid & 63, wid = tid >> 6;
    const int l15 = lane & 15, lg = lane >> 4;
    const int rowB = blockIdx.x * 256;
    const int C0 = blockIdx.y * 64;                     // 64-col block: uniform part & gate
    const int part = (C0 >= 1280) ? 1 : 0;
    const int nn0 = C0 - part * 1280;
    const int gg = nn0 >> 8;
    const int pb = (nn0 & 255) >> 4;                    // base panel of this block (4 panels)

    const unsigned segOff = (unsigned)((((lane & 3) ^ ((lane >> 3) & 3))) * 16);
    unsigned srcA[4];
    #pragma unroll
    for (int i = 0; i < 4; ++i) {
        int rl = (wid * 4 + i) * 16 + (lane >> 2);
        srcA[i] = (unsigned)(rowB + rl) * 512u + segOff;
    }
    unsigned bsrc;
    {
        int cc = tid >> 2, j = tid & 3;
        int np = C0 + cc;
        int nn = np - part * 1280;
        bsrc = (unsigned)((nn * 640 + 128 + part * 256 + ((j ^ ((cc >> 1) & 3)) * 8)) * 2);
    }
    const char* hPB = (const char*)H0h;
    const char* wPB = (const char*)WT;

    f32x4 acc[4][4];
    #pragma unroll
    for (int rt = 0; rt < 4; ++rt)
        #pragma unroll
        for (int ct = 0; ct < 4; ++ct) acc[rt][ct] = (f32x4)0.f;

    const int xw = (l15 >> 1) & 3;

    auto STAGE = [&](int st, int buf) {
        #pragma unroll
        for (int i = 0; i < 4; ++i)
            gload16(hPB + srcA[i] + (unsigned)st * 64u, &Asm[buf][(wid * 4 + i) * 1024 + lane * 16]);
        gload16(wPB + bsrc + (unsigned)st * 64u, &Bsm[buf][tid * 16]);
    };
    auto COMPUTE = [&](int buf) {
        half8 aF[4];
        #pragma unroll
        for (int rt = 0; rt < 4; ++rt)
            aF[rt] = *(const half8*)&Asm[buf][(wid * 64 + rt * 16 + l15) * 64 + ((lg ^ xw) * 16)];
        #pragma unroll
        for (int ct = 0; ct < 4; ++ct) {
            int cc = ct * 16 + l15;
            half8 bF = *(const half8*)&Bsm[buf][cc * 64 + ((lg ^ ((cc >> 1) & 3)) * 16)];
            #pragma unroll
            for (int rt = 0; rt < 4; ++rt)
                acc[rt][ct] = __builtin_amdgcn_mfma_f32_16x16x32_f16(aF[rt], bF, acc[rt][ct], 0, 0, 0);
        }
    };
    auto WAITB = [&](bool counted) {
        if (counted) vwaitN<5>(); else vwaitN<0>();
        __builtin_amdgcn_s_barrier();
        __builtin_amdgcn_sched_barrier(0);
    };

    STAGE(0, 0); STAGE(1, 1); WAITB(true);
    #pragma unroll
    for (int S = 0; S < 8; ++S) {
        if (S + 2 < 8) STAGE(S + 2, (S + 2) % 3);
        COMPUTE(S % 3);
        if (S < 7) WAITB(S + 2 < 8);
    }

    #pragma unroll
    for (int rt = 0; rt < 4; ++rt)
        #pragma unroll
        for (int ct = 0; ct < 4; ++ct)
            #pragma unroll
            for (int q = 0; q < 4; ++q) {
                int id = rowB + wid * 64 + rt * 16 + lg * 4 + q;
                Gp[(((size_t)(id * 2 + part) * 16 + pb + ct) * 5 + gg) * 16 + l15] = acc[rt][ct][q];
            }
}

// Level-1 gather-add-gate, XCD-resident: XCD k owns panel-pair k (cols 32k..32k+32),
// sweeping all 32768 rows. Hot set/XCD ~4.2MB (Gp 2.6 + tabP 1.3 + H0c 0.26) ~= L2.
// Block: 32 cols (pair) x 8 rows, 32 row-iters. Stores: h 64B full lines, c 128B.
__global__ __launch_bounds__(256) void lvl1_combine(
    const float* __restrict__ tabP, const float* __restrict__ Gp,
    const float* __restrict__ H0c, const int* __restrict__ ids,
    _Float16* __restrict__ h_out, float* __restrict__ c_out)
{
    const int tid = threadIdx.x;
    const int c32 = tid & 31, rq = tid >> 5;            // 8 rows per iter
    const int bid = blockIdx.x;                          // 1024 blocks
    const int xcd = bid & 7, rank = bid >> 3;            // rank 0..127
    const int p = xcd * 2 + (c32 >> 4);                  // panel
    const int l15 = c32 & 15;
    const int col = p * 16 + l15;
    #pragma unroll 4
    for (int it = 0; it < 32; ++it) {
        int row = rank * 256 + it * 8 + rq;
        int b = row >> 7, j = row & 127;
        const int* idr = ids + b * NODES_;
        int idp = idr[256 + j];
        int idA = idr[2 * j];
        int idB = idr[2 * j + 1];
        const float* tp = tabP + ((size_t)(idp * 16 + p) * 5) * 16 + l15;
        const float* g1 = Gp + (((size_t)(idA * 2 + 0) * 16 + p) * 5) * 16 + l15;
        const float* g2 = Gp + (((size_t)(idB * 2 + 1) * 16 + p) * 5) * 16 + l15;
        float pre0 = tp[0]  + g1[0]  + g2[0];
        float pre1 = tp[16] + g1[16] + g2[16];
        float pre2 = tp[32] + g1[32] + g2[32];
        float pre3 = tp[48] + g1[48] + g2[48];
        float pre4 = tp[64] + g1[64] + g2[64];
        float c1 = H0c[idA * 256 + col], c2 = H0c[idB * 256 + col];
        float vi = sigm(pre0), vo = sigm(pre1), vu = tanh_f(pre2);
        float vf0 = sigm(pre3), vf1 = sigm(pre4);
        float c = vi * vu + vf0 * c1 + vf1 * c2;
        h_out[(size_t)row * 256 + col] = (_Float16)(vo * tanh_f(c));
        c_out[(size_t)row * 256 + col] = c;
    }
}

// Tree-level cell vJ (R13): K=640, m97-structure + counted-vmcnt 3-buffer pipeline.
template<int RT>
__global__ __launch_bounds__(256, (RT >= 4 ? 2 : 4)) void cellJ(
    const _Float16* __restrict__ WT, const float* __restrict__ bias,
    const _Float16* __restrict__ embh, const int* __restrict__ ids,
    const _Float16* __restrict__ h_prev, const float* __restrict__ c_prev,
    _Float16* __restrict__ h_out, float* __restrict__ c_out,
    int n, int ln, int off, int nx)
{
    constexpr int BM = RT * 64;
    __shared__ __align__(16) char Asm[3][BM * 64];
    __shared__ __align__(16) char Bsm[3][5120];
    const int tid = threadIdx.x, lane = tid & 63, wid = tid >> 6;
    const int l15 = lane & 15, lg = lane >> 4;

    int bid = blockIdx.x, x, y;
    if ((nx & 7) == 0) { int xcd = bid & 7, rank = bid >> 3; x = xcd * (nx >> 3) + (rank >> 4); y = rank & 15; }
    else { x = bid >> 4; y = bid & 15; }
    const int rowB = x * BM;
    const int t0 = y * 16;

    const unsigned segOff = (unsigned)((((lane & 3) ^ ((lane >> 3) & 3))) * 16);
    unsigned srcX[RT], srcA[RT];
    #pragma unroll
    for (int i = 0; i < RT; ++i) {
        int rl = (wid * RT + i) * 16 + (lane >> 2);
        int r = rowB + rl;
        int b = r >> ln, j = r & (n - 1);
        srcX[i] = (unsigned)ids[b * NODES_ + off + j] * 256u + segOff;
        srcA[i] = (unsigned)r * 1024u + segOff;
    }
    unsigned bsrc0, bsrc1 = 0;
    {
        int nr = tid >> 2, j = tid & 3;
        int ng = (nr >> 4) * 256 + t0 + (nr & 15);
        bsrc0 = (unsigned)((ng * 640 + ((j ^ ((nr >> 1) & 3)) * 8)) * 2);
        if (wid == 0) {
            int ng2 = 1024 + t0 + (tid >> 2);
            int seg2 = (tid & 3) ^ ((tid >> 3) & 3);
            bsrc1 = (unsigned)((ng2 * 640 + seg2 * 8) * 2);
        }
    }
    const char* hPB = (const char*)h_prev;
    const char* xPB = (const char*)embh;
    const char* wPB = (const char*)WT;

    f32x4 acc[RT][5];
    #pragma unroll
    for (int rt = 0; rt < RT; ++rt)
        #pragma unroll
        for (int g = 0; g < 5; ++g) acc[rt][g] = (f32x4)0.f;

    const int xw = (l15 >> 1) & 3;

    auto STAGE = [&](int st, int buf) {
        #pragma unroll
        for (int i = 0; i < RT; ++i) {
            const char* bp; unsigned sa;
            if (st < 4) { bp = xPB; sa = srcX[i] + (unsigned)st * 64u; }
            else { bp = hPB; sa = srcA[i] + (unsigned)(st - 4) * 64u; }
            gload16(bp + sa, &Asm[buf][(wid * RT + i) * 1024 + lane * 16]);
        }
        gload16(wPB + bsrc0 + (unsigned)st * 64u, &Bsm[buf][tid * 16]);
        if (wid == 0) gload16(wPB + bsrc1 + (unsigned)st * 64u, &Bsm[buf][4096 + tid * 16]);
    };
    auto COMPUTE = [&](int buf) {
        half8 aF[RT];
        #pragma unroll
        for (int rt = 0; rt < RT; ++rt)
            aF[rt] = *(const half8*)&Asm[buf][(wid * RT * 16 + rt * 16 + l15) * 64 + ((lg ^ xw) * 16)];
        #pragma unroll
        for (int g = 0; g < 5; ++g) {
            half8 bF = *(const half8*)&Bsm[buf][(g * 16 + l15) * 64 + ((lg ^ xw) * 16)];
            #pragma unroll
            for (int rt = 0; rt < RT; ++rt)
                acc[rt][g] = __builtin_amdgcn_mfma_f32_16x16x32_f16(aF[rt], bF, acc[rt][g], 0, 0, 0);
        }
    };
    auto WAITB = [&](bool counted) {
        if (counted) { if (wid == 0) vwaitN<RT + 2>(); else vwaitN<RT + 1>(); }
        else vwaitN<0>();
        __builtin_amdgcn_s_barrier();
        __builtin_amdgcn_sched_barrier(0);
    };

    STAGE(0, 0);
    STAGE(1, 1);
    WAITB(true);

    #pragma unroll
    for (int S = 0; S < 20; ++S) {
        if (S + 2 < 20) STAGE(S + 2, (S + 2) % 3);
        COMPUTE(S % 3);
        if (S < 19) WAITB(S + 2 < 20);
    }

    const int tcol = t0 + l15;
    const float b0 = bias[tcol], b1 = bias[256 + tcol], b2 = bias[512 + tcol];
    const float b3 = bias[768 + tcol], b4 = bias[1024 + tcol];
    #pragma unroll
    for (int rt = 0; rt < RT; ++rt) {
        #pragma unroll
        for (int q = 0; q < 4; ++q) {
            int row = rowB + wid * (RT * 16) + rt * 16 + lg * 4 + q;
            const float* cpp = c_prev + (size_t)row * 512 + tcol;
            float c1 = cpp[0], c2 = cpp[256];
            float vi  = sigm(acc[rt][0][q] + b0);
            float vo  = sigm(acc[rt][1][q] + b1);
            float vu  = tanh_f(acc[rt][2][q] + b2);
            float vf0 = sigm(acc[rt][3][q] + b3);
            float vf1 = sigm(acc[rt][4][q] + b4);
            float c = vi * vu + vf0 * c1 + vf1 * c2;
            size_t ob = (size_t)row * 256 + tcol;
            h_out[ob] = (_Float16)(vo * tanh_f(c));
            c_out[ob] = c;
        }
    }
}

// pred[b] = relu(h_root[b] @ Wl1 + bl1) @ Wl2 + bl2
__global__ void head_kernel(const _Float16* __restrict__ hroot,
    const float* __restrict__ Wl1, const float* __restrict__ bl1,
    const float* __restrict__ Wl2, const float* __restrict__ bl2,
    float* __restrict__ out)
{
    __shared__ float hrow[H_];
    __shared__ float red[256];
    int b = blockIdx.x; int tid = threadIdx.x;
    hrow[tid] = (float)hroot[(size_t)b * H_ + tid];
    __syncthreads();
    float v = 0.f;
    if (tid < 100) {
        float s = bl1[tid];
        for (int k = 0; k < H_; ++k) s = fmaf(hrow[k], Wl1[k * 100 + tid], s);
        v = fmaxf(s, 0.f) * Wl2[tid];
    }
    red[tid] = v;
    __syncthreads();
    for (int s = 128; s > 0; s >>= 1) { if (tid < s) red[tid] += red[tid + s]; __syncthreads(); }
    if (tid == 0) out[b] = red[0] + bl2[0];
}

extern "C" void kernel_launch(void* const* d_in, const int* in_sizes, int n_in,
                              void* d_out, int out_size, void* d_ws, size_t ws_size,
                              hipStream_t stream) {
    const int*   ids    = (const int*)d_in[0];
    const float* emb    = (const float*)d_in[1];
    const float* Wioux  = (const float*)d_in[2];
    const float* bioux  = (const float*)d_in[3];
    const float* Wiouh1 = (const float*)d_in[4];
    const float* biouh1 = (const float*)d_in[5];
    const float* Wiouh2 = (const float*)d_in[6];
    const float* biouh2 = (const float*)d_in[7];
    const float* Wfx    = (const float*)d_in[8];
    const float* bfx    = (const float*)d_in[9];
    const float* Wfh11  = (const float*)d_in[10];
    const float* bfh11  = (const float*)d_in[11];
    const float* Wfh12  = (const float*)d_in[12];
    const float* bfh12  = (const float*)d_in[13];
    const float* Wfh21  = (const float*)d_in[14];
    const float* bfh21  = (const float*)d_in[15];
    const float* Wfh22  = (const float*)d_in[16];
    const float* bfh22  = (const float*)d_in[17];
    const float* Wl1    = (const float*)d_in[18];
    const float* bl1    = (const float*)d_in[19];
    const float* Wl2    = (const float*)d_in[20];
    const float* bl2    = (const float*)d_in[21];
    float* out = (float*)d_out;

    // ws layout (bytes)
    char* wsb = (char*)d_ws;
    _Float16* WT   = (_Float16*)(wsb);                   //  1,638,400
    _Float16* embh = (_Float16*)(wsb + 1638400);         //    524,288
    float*    bias = (float*)(wsb + 2162688);            //      5,120
    float*    tabP = (float*)(wsb + 2167808);            // 10,485,760
    _Float16* H0h  = (_Float16*)(wsb + 12653568);        //  1,048,576
    float*    H0c  = (float*)(wsb + 13702144);           //  2,097,152
    _Float16* hA   = (_Float16*)(wsb + 15799296);        //  8,388,608
    _Float16* hB   = (_Float16*)(wsb + 24187904);        // 16,777,216
    float*    cA   = (float*)(wsb + 40965120);           // 16,777,216
    float*    cB   = (float*)(wsb + 57742336);           // 33,554,432
    float*    Gp   = (float*)(wsb + 91296768);           // 20,971,520 -> ends 112,268,288

    build_WT<<<dim3(3200), 256, 0, stream>>>(WT, Wioux, Wfx, Wiouh1, Wfh11, Wfh21, Wiouh2, Wfh12, Wfh22);
    build_bias<<<dim3(5), 256, 0, stream>>>(bias, bioux, biouh1, biouh2, bfx, bfh11, bfh12, bfh21, bfh22);
    build_embh<<<dim3(1024), 256, 0, stream>>>(embh, emb);
    build_table<<<dim3(32, 20), 256, 0, stream>>>(tabP, emb, Wioux, Wfx,
        bioux, biouh1, biouh2, bfx, bfh11, bfh12, bfh21, bfh22);
    build_h0c0<<<dim3(2048), 256, 0, stream>>>(tabP, H0h, H0c);
    build_G<<<dim3(8, 40), 256, 0, stream>>>(WT, H0h, Gp);

    // level 1 via XCD-resident gather-add-gate
    lvl1_combine<<<dim3(1024), 256, 0, stream>>>(tabP, Gp, H0c, ids, hB, cB);

    _Float16 *hp = hB, *hn = hA;
    float    *cp = cB, *cn = cA;
    int off = 384, n = 64, ln = 6;
    for (int lvl = 2; lvl <= 8; ++lvl) {
        int M = B_ * n;
        if (M >= 2048) {                 // lvl 2-5: RT=4, BM=256
            int nx = M / 256;
            cellJ<4><<<dim3(nx * 16), 256, 0, stream>>>(WT, bias, embh, ids, hp, cp, hn, cn, n, ln, off, nx);
        } else if (M >= 1024) {          // lvl 6: RT=2, BM=128
            int nx = M / 128;
            cellJ<2><<<dim3(nx * 16), 256, 0, stream>>>(WT, bias, embh, ids, hp, cp, hn, cn, n, ln, off, nx);
        } else {                         // lvl 7-8: RT=1, BM=64
            int nx = M / 64;
            cellJ<1><<<dim3(nx * 16), 256, 0, stream>>>(WT, bias, embh, ids, hp, cp, hn, cn, n, ln, off, nx);
        }
        off += n; n >>= 1; --ln;
        _Float16* t1 = hp; hp = hn; hn = t1;
        float*    t2 = cp; cp = cn; cn = t2;
    }

    head_kernel<<<dim3(256), 256, 0, stream>>>(hp, Wl1, bl1, Wl2, bl2, out);
}

// Round 17
// 237.648 us; speedup vs baseline: 1.3126x; 1.0237x over previous
//
#include <hip/hip_runtime.h>
#include <math.h>

#define B_ 256
#define L_ 256
#define V_ 2048
#define DIN_ 128
#define H_ 256
#define NODES_ 511

typedef _Float16 half8 __attribute__((ext_vector_type(8)));
typedef float f32x4 __attribute__((ext_vector_type(4)));

__device__ __forceinline__ float sigm(float x) { return 1.f / (1.f + __expf(-x)); }
__device__ __forceinline__ float tanh_f(float x) {
    float xc = fminf(fmaxf(x, -15.f), 15.f);
    float e = __expf(2.f * xc);
    return (e - 1.f) / (e + 1.f);
}
__device__ __forceinline__ void gload16(const void* g, void* l) {
    __builtin_amdgcn_global_load_lds((const __attribute__((address_space(1))) unsigned int*)g,
                                     (__attribute__((address_space(3))) unsigned int*)l, 16, 0, 0);
}
template<int N> __device__ __forceinline__ void vwaitN() {
    asm volatile("s_waitcnt vmcnt(%0)" :: "i"(N) : "memory");
}

// WT[nn][k] fp16: FULL fused weights. nn = g*256+t (g:0=i,1=o,2=u,3=f0,4=f1),
// k: [0,128)=x, [128,384)=h1, [384,640)=h2
__global__ void build_WT(_Float16* __restrict__ WT,
    const float* __restrict__ Wioux, const float* __restrict__ Wfx,
    const float* __restrict__ Wiouh1, const float* __restrict__ Wfh11, const float* __restrict__ Wfh21,
    const float* __restrict__ Wiouh2, const float* __restrict__ Wfh12, const float* __restrict__ Wfh22)
{
    int e = blockIdx.x * 256 + threadIdx.x;   // < 1280*640
    int nn = e / 640, k = e - nn * 640;
    int g = nn >> 8, t = nn & 255;
    float v;
    if (k < 128) {
        v = (g < 3) ? Wioux[k * 768 + nn] : Wfx[k * 256 + t];
    } else if (k < 384) {
        int kp = k - 128;
        v = (g < 3) ? Wiouh1[kp * 768 + nn] : ((g == 3) ? Wfh11[kp * 256 + t] : Wfh21[kp * 256 + t]);
    } else {
        int kp = k - 384;
        v = (g < 3) ? Wiouh2[kp * 768 + nn] : ((g == 3) ? Wfh12[kp * 256 + t] : Wfh22[kp * 256 + t]);
    }
    WT[e] = (_Float16)v;
}

// tabP[id][panel][gate][16] f32 = emb(id,:) @ Wx_fused + bias_total, panel-contiguous.
__global__ __launch_bounds__(256) void build_table(float* __restrict__ tabP, const float* __restrict__ emb,
    const float* __restrict__ Wioux, const float* __restrict__ Wfx,
    const float* __restrict__ bioux, const float* __restrict__ biouh1, const float* __restrict__ biouh2,
    const float* __restrict__ bfx, const float* __restrict__ bfh11, const float* __restrict__ bfh12,
    const float* __restrict__ bfh21, const float* __restrict__ bfh22)
{
    __shared__ float As[64][33];
    __shared__ float Ws[32][65];
    const int tid = threadIdx.x, tx = tid & 15, ty = tid >> 4;
    const int i0 = blockIdx.x * 64, c0 = blockIdx.y * 64;
    const int g = c0 >> 8;
    float acc[4][4];
    #pragma unroll
    for (int i = 0; i < 4; ++i)
        #pragma unroll
        for (int j = 0; j < 4; ++j) acc[i][j] = 0.f;

    for (int k0 = 0; k0 < 128; k0 += 32) {
        #pragma unroll
        for (int it = 0; it < 2; ++it) {
            int f = tid + it * 256;
            int row = f >> 3, kk = (f & 7) * 4;
            int gr = i0 + row;
            float4 av = (gr == 0) ? make_float4(0.f, 0.f, 0.f, 0.f)
                                  : *(const float4*)(emb + (size_t)gr * 128 + k0 + kk);
            As[row][kk] = av.x; As[row][kk + 1] = av.y; As[row][kk + 2] = av.z; As[row][kk + 3] = av.w;
            int k = f >> 4, cc = (f & 15) * 4;
            int col = c0 + cc;
            float4 wv = (g < 3) ? *(const float4*)(Wioux + (size_t)(k0 + k) * 768 + col)
                                : *(const float4*)(Wfx + (size_t)(k0 + k) * 256 + (col & 255));
            Ws[k][cc] = wv.x; Ws[k][cc + 1] = wv.y; Ws[k][cc + 2] = wv.z; Ws[k][cc + 3] = wv.w;
        }
        __syncthreads();
        #pragma unroll 8
        for (int k = 0; k < 32; ++k) {
            float a[4], w[4];
            #pragma unroll
            for (int i = 0; i < 4; ++i) a[i] = As[ty * 4 + i][k];
            #pragma unroll
            for (int j = 0; j < 4; ++j) w[j] = Ws[k][tx * 4 + j];
            #pragma unroll
            for (int i = 0; i < 4; ++i)
                #pragma unroll
                for (int j = 0; j < 4; ++j) acc[i][j] = fmaf(a[i], w[j], acc[i][j]);
        }
        __syncthreads();
    }
    #pragma unroll
    for (int j = 0; j < 4; ++j) {
        int col = c0 + tx * 4 + j; int t = col & 255;
        int p = t >> 4, q = t & 15;
        float bs = (g < 3) ? (bioux[col] + biouh1[col] + biouh2[col])
                 : (g == 3) ? (bfx[t] + bfh11[t] + bfh12[t])
                            : (bfx[t] + bfh21[t] + bfh22[t]);
        #pragma unroll
        for (int i = 0; i < 4; ++i) {
            int id = i0 + ty * 4 + i;
            tabP[((size_t)(id * 16 + p) * 5 + g) * 16 + q] = acc[i][j] + bs;
        }
    }
}

// Level-0 result depends only on token id: H0h/H0c[id][t] (reads panel-contiguous tabP)
__global__ void build_h0c0(const float* __restrict__ tabP, _Float16* __restrict__ H0h, float* __restrict__ H0c) {
    int id = blockIdx.x, t = threadIdx.x;
    int p = t >> 4, q = t & 15;
    const float* tp = tabP + ((size_t)(id * 16 + p) * 5) * 16 + q;
    float vi = sigm(tp[0]), vo = sigm(tp[16]), vu = tanh_f(tp[32]);
    float c = vi * vu;
    H0h[id * 256 + t] = (_Float16)(vo * tanh_f(c));
    H0c[id * 256 + t] = c;
}

// Gp[id][part][panel][gate][16] f32 = H0h(id,:) @ [Wh1 | Wh2]. M=2048, K=256, N=2560.
__global__ __launch_bounds__(256, 2) void build_G(
    const _Float16* __restrict__ WT, const _Float16* __restrict__ H0h, float* __restrict__ Gp)
{
    __shared__ __align__(16) char Asm[3][256 * 64];
    __shared__ __align__(16) char Bsm[3][4096];
    const int tid = threadIdx.x, lane = tid & 63, wid = tid >> 6;
    const int l15 = lane & 15, lg = lane >> 4;
    const int rowB = blockIdx.x * 256;
    const int C0 = blockIdx.y * 64;
    const int part = (C0 >= 1280) ? 1 : 0;
    const int nn0 = C0 - part * 1280;
    const int gg = nn0 >> 8;
    const int pb = (nn0 & 255) >> 4;

    const unsigned segOff = (unsigned)((((lane & 3) ^ ((lane >> 3) & 3))) * 16);
    unsigned srcA[4];
    #pragma unroll
    for (int i = 0; i < 4; ++i) {
        int rl = (wid * 4 + i) * 16 + (lane >> 2);
        srcA[i] = (unsigned)(rowB + rl) * 512u + segOff;
    }
    unsigned bsrc;
    {
        int cc = tid >> 2, j = tid & 3;
        int np = C0 + cc;
        int nn = np - part * 1280;
        bsrc = (unsigned)((nn * 640 + 128 + part * 256 + ((j ^ ((cc >> 1) & 3)) * 8)) * 2);
    }
    const char* hPB = (const char*)H0h;
    const char* wPB = (const char*)WT;

    f32x4 acc[4][4];
    #pragma unroll
    for (int rt = 0; rt < 4; ++rt)
        #pragma unroll
        for (int ct = 0; ct < 4; ++ct) acc[rt][ct] = (f32x4)0.f;

    const int xw = (l15 >> 1) & 3;

    auto STAGE = [&](int st, int buf) {
        #pragma unroll
        for (int i = 0; i < 4; ++i)
            gload16(hPB + srcA[i] + (unsigned)st * 64u, &Asm[buf][(wid * 4 + i) * 1024 + lane * 16]);
        gload16(wPB + bsrc + (unsigned)st * 64u, &Bsm[buf][tid * 16]);
    };
    auto COMPUTE = [&](int buf) {
        half8 aF[4];
        #pragma unroll
        for (int rt = 0; rt < 4; ++rt)
            aF[rt] = *(const half8*)&Asm[buf][(wid * 64 + rt * 16 + l15) * 64 + ((lg ^ xw) * 16)];
        #pragma unroll
        for (int ct = 0; ct < 4; ++ct) {
            int cc = ct * 16 + l15;
            half8 bF = *(const half8*)&Bsm[buf][cc * 64 + ((lg ^ ((cc >> 1) & 3)) * 16)];
            #pragma unroll
            for (int rt = 0; rt < 4; ++rt)
                acc[rt][ct] = __builtin_amdgcn_mfma_f32_16x16x32_f16(aF[rt], bF, acc[rt][ct], 0, 0, 0);
        }
    };
    auto WAITB = [&](bool counted) {
        if (counted) vwaitN<5>(); else vwaitN<0>();
        __builtin_amdgcn_s_barrier();
        __builtin_amdgcn_sched_barrier(0);
    };

    STAGE(0, 0); STAGE(1, 1); WAITB(true);
    #pragma unroll
    for (int S = 0; S < 8; ++S) {
        if (S + 2 < 8) STAGE(S + 2, (S + 2) % 3);
        COMPUTE(S % 3);
        if (S < 7) WAITB(S + 2 < 8);
    }

    #pragma unroll
    for (int rt = 0; rt < 4; ++rt)
        #pragma unroll
        for (int ct = 0; ct < 4; ++ct)
            #pragma unroll
            for (int q = 0; q < 4; ++q) {
                int id = rowB + wid * 64 + rt * 16 + lg * 4 + q;
                Gp[(((size_t)(id * 2 + part) * 16 + pb + ct) * 5 + gg) * 16 + l15] = acc[rt][ct][q];
            }
}

// Level-1 gather-add-gate, XCD-resident (R15-verified).
__global__ __launch_bounds__(256) void lvl1_combine(
    const float* __restrict__ tabP, const float* __restrict__ Gp,
    const float* __restrict__ H0c, const int* __restrict__ ids,
    _Float16* __restrict__ h_out, float* __restrict__ c_out)
{
    const int tid = threadIdx.x;
    const int c32 = tid & 31, rq = tid >> 5;
    const int bid = blockIdx.x;
    const int xcd = bid & 7, rank = bid >> 3;
    const int p = xcd * 2 + (c32 >> 4);
    const int l15 = c32 & 15;
    const int col = p * 16 + l15;
    #pragma unroll 4
    for (int it = 0; it < 32; ++it) {
        int row = rank * 256 + it * 8 + rq;
        int b = row >> 7, j = row & 127;
        const int* idr = ids + b * NODES_;
        int idp = idr[256 + j];
        int idA = idr[2 * j];
        int idB = idr[2 * j + 1];
        const float* tp = tabP + ((size_t)(idp * 16 + p) * 5) * 16 + l15;
        const float* g1 = Gp + (((size_t)(idA * 2 + 0) * 16 + p) * 5) * 16 + l15;
        const float* g2 = Gp + (((size_t)(idB * 2 + 1) * 16 + p) * 5) * 16 + l15;
        float pre0 = tp[0]  + g1[0]  + g2[0];
        float pre1 = tp[16] + g1[16] + g2[16];
        float pre2 = tp[32] + g1[32] + g2[32];
        float pre3 = tp[48] + g1[48] + g2[48];
        float pre4 = tp[64] + g1[64] + g2[64];
        float c1 = H0c[idA * 256 + col], c2 = H0c[idB * 256 + col];
        float vi = sigm(pre0), vo = sigm(pre1), vu = tanh_f(pre2);
        float vf0 = sigm(pre3), vf1 = sigm(pre4);
        float c = vi * vu + vf0 * c1 + vf1 * c2;
        h_out[(size_t)row * 256 + col] = (_Float16)(vo * tanh_f(c));
        c_out[(size_t)row * 256 + col] = c;
    }
}

// Tree-level cell vK: K=512 (h-part only; x + bias via panel-contiguous tabP in epilogue).
// m97-structure + counted-vmcnt 3-buffer pipeline. BK=32, 16 K-steps.
template<int RT>
__global__ __launch_bounds__(256, (RT >= 4 ? 2 : 4)) void cellK(
    const _Float16* __restrict__ WT, const float* __restrict__ tabP,
    const int* __restrict__ ids,
    const _Float16* __restrict__ h_prev, const float* __restrict__ c_prev,
    _Float16* __restrict__ h_out, float* __restrict__ c_out,
    int n, int ln, int off, int nx)
{
    constexpr int BM = RT * 64;
    __shared__ __align__(16) char Asm[3][BM * 64];
    __shared__ __align__(16) char Bsm[3][5120];
    const int tid = threadIdx.x, lane = tid & 63, wid = tid >> 6;
    const int l15 = lane & 15, lg = lane >> 4;

    int bid = blockIdx.x, x, y;
    if ((nx & 7) == 0) { int xcd = bid & 7, rank = bid >> 3; x = xcd * (nx >> 3) + (rank >> 4); y = rank & 15; }
    else { x = bid >> 4; y = bid & 15; }
    const int rowB = x * BM;
    const int t0 = y * 16;

    const unsigned segOff = (unsigned)((((lane & 3) ^ ((lane >> 3) & 3))) * 16);
    unsigned srcA[RT];
    #pragma unroll
    for (int i = 0; i < RT; ++i) {
        int rl = (wid * RT + i) * 16 + (lane >> 2);
        srcA[i] = (unsigned)(rowB + rl) * 1024u + segOff;   // [h1|h2] row = 1024B
    }
    unsigned bsrc0, bsrc1 = 0;
    {
        int nr = tid >> 2, j = tid & 3;
        int ng = (nr >> 4) * 256 + t0 + (nr & 15);
        bsrc0 = (unsigned)((ng * 640 + 128 + ((j ^ ((nr >> 1) & 3)) * 8)) * 2);
        if (wid == 0) {
            int ng2 = 1024 + t0 + (tid >> 2);
            int seg2 = (tid & 3) ^ ((tid >> 3) & 3);
            bsrc1 = (unsigned)((ng2 * 640 + 128 + seg2 * 8) * 2);
        }
    }
    const char* hPB = (const char*)h_prev;
    const char* wPB = (const char*)WT;

    f32x4 acc[RT][5];
    #pragma unroll
    for (int rt = 0; rt < RT; ++rt)
        #pragma unroll
        for (int g = 0; g < 5; ++g) acc[rt][g] = (f32x4)0.f;

    const int xw = (l15 >> 1) & 3;

    auto STAGE = [&](int st, int buf) {
        #pragma unroll
        for (int i = 0; i < RT; ++i)
            gload16(hPB + srcA[i] + (unsigned)st * 64u, &Asm[buf][(wid * RT + i) * 1024 + lane * 16]);
        gload16(wPB + bsrc0 + (unsigned)st * 64u, &Bsm[buf][tid * 16]);
        if (wid == 0) gload16(wPB + bsrc1 + (unsigned)st * 64u, &Bsm[buf][4096 + tid * 16]);
    };
    auto COMPUTE = [&](int buf) {
        half8 aF[RT];
        #pragma unroll
        for (int rt = 0; rt < RT; ++rt)
            aF[rt] = *(const half8*)&Asm[buf][(wid * RT * 16 + rt * 16 + l15) * 64 + ((lg ^ xw) * 16)];
        #pragma unroll
        for (int g = 0; g < 5; ++g) {
            half8 bF = *(const half8*)&Bsm[buf][(g * 16 + l15) * 64 + ((lg ^ xw) * 16)];
            #pragma unroll
            for (int rt = 0; rt < RT; ++rt)
                acc[rt][g] = __builtin_amdgcn_mfma_f32_16x16x32_f16(aF[rt], bF, acc[rt][g], 0, 0, 0);
        }
    };
    auto WAITB = [&](bool counted) {
        if (counted) { if (wid == 0) vwaitN<RT + 2>(); else vwaitN<RT + 1>(); }
        else vwaitN<0>();
        __builtin_amdgcn_s_barrier();
        __builtin_amdgcn_sched_barrier(0);
    };

    STAGE(0, 0);
    STAGE(1, 1);
    WAITB(true);

    #pragma unroll
    for (int S = 0; S < 16; ++S) {
        if (S + 2 < 16) STAGE(S + 2, (S + 2) % 3);
        COMPUTE(S % 3);
        if (S < 15) WAITB(S + 2 < 16);
    }

    // ---- fused epilogue: x-part + bias via tabP (f32, panel-contiguous), c from c_prev.
    const int tcol = t0 + l15;
    #pragma unroll
    for (int rt = 0; rt < RT; ++rt) {
        #pragma unroll
        for (int q = 0; q < 4; ++q) {
            int row = rowB + wid * (RT * 16) + rt * 16 + lg * 4 + q;
            int b = row >> ln, j = row & (n - 1);
            int idp = ids[b * NODES_ + off + j];
            const float* tp = tabP + ((size_t)(idp * 16 + y) * 5) * 16 + l15;
            const float* cpp = c_prev + (size_t)row * 512 + tcol;
            float c1 = cpp[0], c2 = cpp[256];
            float vi  = sigm(acc[rt][0][q] + tp[0]);
            float vo  = sigm(acc[rt][1][q] + tp[16]);
            float vu  = tanh_f(acc[rt][2][q] + tp[32]);
            float vf0 = sigm(acc[rt][3][q] + tp[48]);
            float vf1 = sigm(acc[rt][4][q] + tp[64]);
            float c = vi * vu + vf0 * c1 + vf1 * c2;
            size_t ob = (size_t)row * 256 + tcol;
            h_out[ob] = (_Float16)(vo * tanh_f(c));
            c_out[ob] = c;
        }
    }
}

// pred[b] = relu(h_root[b] @ Wl1 + bl1) @ Wl2 + bl2
__global__ void head_kernel(const _Float16* __restrict__ hroot,
    const float* __restrict__ Wl1, const float* __restrict__ bl1,
    const float* __restrict__ Wl2, const float* __restrict__ bl2,
    float* __restrict__ out)
{
    __shared__ float hrow[H_];
    __shared__ float red[256];
    int b = blockIdx.x; int tid = threadIdx.x;
    hrow[tid] = (float)hroot[(size_t)b * H_ + tid];
    __syncthreads();
    float v = 0.f;
    if (tid < 100) {
        float s = bl1[tid];
        for (int k = 0; k < H_; ++k) s = fmaf(hrow[k], Wl1[k * 100 + tid], s);
        v = fmaxf(s, 0.f) * Wl2[tid];
    }
    red[tid] = v;
    __syncthreads();
    for (int s = 128; s > 0; s >>= 1) { if (tid < s) red[tid] += red[tid + s]; __syncthreads(); }
    if (tid == 0) out[b] = red[0] + bl2[0];
}

extern "C" void kernel_launch(void* const* d_in, const int* in_sizes, int n_in,
                              void* d_out, int out_size, void* d_ws, size_t ws_size,
                              hipStream_t stream) {
    const int*   ids    = (const int*)d_in[0];
    const float* emb    = (const float*)d_in[1];
    const float* Wioux  = (const float*)d_in[2];
    const float* bioux  = (const float*)d_in[3];
    const float* Wiouh1 = (const float*)d_in[4];
    const float* biouh1 = (const float*)d_in[5];
    const float* Wiouh2 = (const float*)d_in[6];
    const float* biouh2 = (const float*)d_in[7];
    const float* Wfx    = (const float*)d_in[8];
    const float* bfx    = (const float*)d_in[9];
    const float* Wfh11  = (const float*)d_in[10];
    const float* bfh11  = (const float*)d_in[11];
    const float* Wfh12  = (const float*)d_in[12];
    const float* bfh12  = (const float*)d_in[13];
    const float* Wfh21  = (const float*)d_in[14];
    const float* bfh21  = (const float*)d_in[15];
    const float* Wfh22  = (const float*)d_in[16];
    const float* bfh22  = (const float*)d_in[17];
    const float* Wl1    = (const float*)d_in[18];
    const float* bl1    = (const float*)d_in[19];
    const float* Wl2    = (const float*)d_in[20];
    const float* bl2    = (const float*)d_in[21];
    float* out = (float*)d_out;

    // ws layout (bytes)
    char* wsb = (char*)d_ws;
    _Float16* WT   = (_Float16*)(wsb);                   //  1,638,400
    float*    tabP = (float*)(wsb + 2167808);            // 10,485,760
    _Float16* H0h  = (_Float16*)(wsb + 12653568);        //  1,048,576
    float*    H0c  = (float*)(wsb + 13702144);           //  2,097,152
    _Float16* hA   = (_Float16*)(wsb + 15799296);        //  8,388,608
    _Float16* hB   = (_Float16*)(wsb + 24187904);        // 16,777,216
    float*    cA   = (float*)(wsb + 40965120);           // 16,777,216
    float*    cB   = (float*)(wsb + 57742336);           // 33,554,432
    float*    Gp   = (float*)(wsb + 91296768);           // 20,971,520 -> ends 112,268,288

    build_WT<<<dim3(3200), 256, 0, stream>>>(WT, Wioux, Wfx, Wiouh1, Wfh11, Wfh21, Wiouh2, Wfh12, Wfh22);
    build_table<<<dim3(32, 20), 256, 0, stream>>>(tabP, emb, Wioux, Wfx,
        bioux, biouh1, biouh2, bfx, bfh11, bfh12, bfh21, bfh22);
    build_h0c0<<<dim3(2048), 256, 0, stream>>>(tabP, H0h, H0c);
    build_G<<<dim3(8, 40), 256, 0, stream>>>(WT, H0h, Gp);

    // level 1 via XCD-resident gather-add-gate
    lvl1_combine<<<dim3(1024), 256, 0, stream>>>(tabP, Gp, H0c, ids, hB, cB);

    _Float16 *hp = hB, *hn = hA;
    float    *cp = cB, *cn = cA;
    int off = 384, n = 64, ln = 6;
    for (int lvl = 2; lvl <= 8; ++lvl) {
        int M = B_ * n;
        if (M >= 2048) {                 // lvl 2-5: RT=4, BM=256
            int nx = M / 256;
            cellK<4><<<dim3(nx * 16), 256, 0, stream>>>(WT, tabP, ids, hp, cp, hn, cn, n, ln, off, nx);
        } else if (M >= 1024) {          // lvl 6: RT=2, BM=128
            int nx = M / 128;
            cellK<2><<<dim3(nx * 16), 256, 0, stream>>>(WT, tabP, ids, hp, cp, hn, cn, n, ln, off, nx);
        } else {                         // lvl 7-8: RT=1, BM=64
            int nx = M / 64;
            cellK<1><<<dim3(nx * 16), 256, 0, stream>>>(WT, tabP, ids, hp, cp, hn, cn, n, ln, off, nx);
        }
        off += n; n >>= 1; --ln;
        _Float16* t1 = hp; hp = hn; hn = t1;
        float*    t2 = cp; cp = cn; cn = t2;
    }

    head_kernel<<<dim3(256), 256, 0, stream>>>(hp, Wl1, bl1, Wl2, bl2, out);
}